// Round 1
// baseline (972.360 us; speedup 1.0000x reference)
//
#include <hip/hip_runtime.h>
#include <hip/hip_bf16.h>
#include <cstdint>

#define DEVINL __device__ __forceinline__

using bf16 = __hip_bfloat16;
typedef __bf16 bf16x8 __attribute__((ext_vector_type(8)));
typedef float f32x4 __attribute__((ext_vector_type(4)));

static constexpr int MTOK = 131072;  // B*N tokens

DEVINL void async_ld16(const void* g, void* l) {
  __builtin_amdgcn_global_load_lds(
      (__attribute__((address_space(1))) void*)(g),
      (__attribute__((address_space(3))) void*)(l), 16, 0, 0);
}

DEVINL unsigned short bfbits(float v) {
  bf16 h = __float2bfloat16(v);
  return *reinterpret_cast<unsigned short*>(&h);
}

// ---------------- weights fp32 -> bf16 (concatenated: in_w, out_w, w1, w2) --
__global__ __launch_bounds__(256) void cvt_w(
    const float* __restrict__ w0, const float* __restrict__ w1,
    const float* __restrict__ w2, const float* __restrict__ w3,
    bf16* __restrict__ out) {
  int i = blockIdx.x * 256 + threadIdx.x;
  float v;
  if (i < 196608)      v = w0[i];
  else if (i < 262144) v = w1[i - 196608];
  else if (i < 524288) v = w2[i - 262144];
  else                 v = w3[i - 524288];
  out[i] = __float2bfloat16(v);
}

// ---------------- LayerNorm (+optional window partition), fp32 -> bf16 ------
// one wave per token (C=256 -> 4 elems/lane)
template <bool REMAP>
__global__ __launch_bounds__(256) void ln_kern(
    const float* __restrict__ x, const float* __restrict__ gw,
    const float* __restrict__ bw, bf16* __restrict__ out) {
  const int lane = threadIdx.x & 63;
  const int wv = threadIdx.x >> 6;
  const long tok = (long)blockIdx.x * 4 + wv;
  const float* xr = x + tok * 256;
  float v[4];
#pragma unroll
  for (int i = 0; i < 4; ++i) v[i] = xr[lane + 64 * i];
  float s = v[0] + v[1] + v[2] + v[3];
#pragma unroll
  for (int off = 32; off > 0; off >>= 1) s += __shfl_xor(s, off);
  const float mean = s * (1.0f / 256.0f);
  float q = 0.f;
#pragma unroll
  for (int i = 0; i < 4; ++i) { float d = v[i] - mean; q += d * d; }
#pragma unroll
  for (int off = 32; off > 0; off >>= 1) q += __shfl_xor(q, off);
  const float inv = rsqrtf(q * (1.0f / 256.0f) + 1e-5f);
  long drow;
  if (REMAP) {
    // token -> (window, pos) : w = b*256 + (row/8)*16 + (col/8), t = (row%8)*8 + col%8
    const int b = (int)(tok >> 14);
    const int n = (int)(tok & 16383);
    const int row = n >> 7, col = n & 127;
    const int w = b * 256 + (row >> 3) * 16 + (col >> 3);
    const int t = (row & 7) * 8 + (col & 7);
    drow = ((long)w * 64 + t) * 256;
  } else {
    drow = tok * 256;
  }
#pragma unroll
  for (int i = 0; i < 4; ++i) {
    const int c = lane + 64 * i;
    out[drow + c] = __float2bfloat16((v[i] - mean) * inv * gw[c] + bw[c]);
  }
}

// ---------------- GEMM: C[M,N] = A[M,K] @ B[N,K]^T (+epilogue) --------------
// m97 structure: 128x128 tile, BK=64, global_load_lds w16, XOR-swizzled LDS.
enum { EPI_QKV = 0, EPI_OUTPROJ = 1, EPI_GELU = 2, EPI_RESID = 3 };

template <int K, int EPI>
__global__ __launch_bounds__(256) void gemm_bt(
    const bf16* __restrict__ A, const bf16* __restrict__ Bw,
    const float* __restrict__ bias,
    bf16* __restrict__ oQ, bf16* __restrict__ oK, bf16* __restrict__ oV,
    const float* __restrict__ resid, float* __restrict__ of32,
    bf16* __restrict__ obf, int ldo) {
  __shared__ __align__(16) unsigned short As[128 * 64];
  __shared__ __align__(16) unsigned short Bs[128 * 64];
  const int tid = threadIdx.x;
  const int lane = tid & 63, wv = tid >> 6;
  const int quad = lane >> 4, l16 = lane & 15;
  const int wm = wv >> 1, wn = wv & 1;
  const long m0 = (long)blockIdx.x * 128;
  const int n0 = blockIdx.y * 128;

  const f32x4 fz = {0.f, 0.f, 0.f, 0.f};
  f32x4 acc[4][4];
#pragma unroll
  for (int a = 0; a < 4; ++a) {
#pragma unroll
    for (int b = 0; b < 4; ++b) acc[a][b] = fz;
  }

  for (int k0 = 0; k0 < K; k0 += 64) {
    // stage A,B tiles: slot f holds global 16B-chunk (f&7)^(row&7) of row f>>3
#pragma unroll
    for (int p = 0; p < 4; ++p) {
      const int f = p * 256 + tid;
      const int row = f >> 3;
      const int c8 = (f & 7) ^ (row & 7);
      async_ld16(A + (m0 + row) * K + (k0 + c8 * 8), (char*)As + f * 16);
      async_ld16(Bw + (long)(n0 + row) * K + (k0 + c8 * 8), (char*)Bs + f * 16);
    }
    __syncthreads();
#pragma unroll
    for (int kk = 0; kk < 2; ++kk) {
      bf16x8 af[4], bfr[4];
#pragma unroll
      for (int mt = 0; mt < 4; ++mt) {
        const int row = wm * 64 + mt * 16 + l16;
        const int c8 = (kk * 4 + quad) ^ (row & 7);
        af[mt] = *(const bf16x8*)(As + row * 64 + c8 * 8);
      }
#pragma unroll
      for (int nt = 0; nt < 4; ++nt) {
        const int row = wn * 64 + nt * 16 + l16;
        const int c8 = (kk * 4 + quad) ^ (row & 7);
        bfr[nt] = *(const bf16x8*)(Bs + row * 64 + c8 * 8);
      }
#pragma unroll
      for (int mt = 0; mt < 4; ++mt) {
#pragma unroll
        for (int nt = 0; nt < 4; ++nt) {
          acc[mt][nt] = __builtin_amdgcn_mfma_f32_16x16x32_bf16(
              af[mt], bfr[nt], acc[mt][nt], 0, 0, 0);
        }
      }
    }
    __syncthreads();
  }

  // epilogue: C/D layout col=lane&15, row=quad*4+reg  [m89-verified]
#pragma unroll
  for (int mt = 0; mt < 4; ++mt) {
#pragma unroll
    for (int nt = 0; nt < 4; ++nt) {
      const long mb = m0 + wm * 64 + mt * 16 + quad * 4;
      const int j = n0 + wn * 64 + nt * 16 + l16;
      const float bj = bias[j];
#pragma unroll
      for (int r = 0; r < 4; ++r) {
        const long m = mb + r;
        const float v = acc[mt][nt][r] + bj;
        if constexpr (EPI == EPI_QKV) {
          const int w = (int)(m >> 6), t = (int)(m & 63);
          const int region = j >> 8, hh = (j >> 5) & 7, d = j & 31;
          const long hb = (long)w * 8 + hh;
          if (region == 0)      oQ[(hb * 64 + t) * 32 + d] = __float2bfloat16(v);
          else if (region == 1) oK[(hb * 64 + t) * 32 + d] = __float2bfloat16(v);
          else                  oV[(hb * 32 + d) * 64 + t] = __float2bfloat16(v);  // V^T
        } else if constexpr (EPI == EPI_OUTPROJ) {
          // window-reverse + residual, fp32 out
          const int w = (int)(m >> 6), t = (int)(m & 63);
          const int b = w >> 8, wi = w & 255;
          const int row = (wi >> 4) * 8 + (t >> 3);
          const int col = (wi & 15) * 8 + (t & 7);
          const long addr = ((long)b * 16384 + row * 128 + col) * 256 + j;
          of32[addr] = v + resid[addr];
        } else if constexpr (EPI == EPI_GELU) {
          const float g = 0.5f * v * (1.0f + erff(v * 0.70710678118654752f));
          obf[m * (long)ldo + j] = __float2bfloat16(g);
        } else {  // EPI_RESID: accumulate into d_out (holds x2)
          const long addr = m * 256 + j;
          of32[addr] += v;
        }
      }
    }
  }
}

// ---------------- fused window attention ------------------------------------
// 1 block / window (64 tokens); wave wv handles heads 2wv, 2wv+1.
__global__ __launch_bounds__(256) void attn_kern(
    const bf16* __restrict__ Qb, const bf16* __restrict__ Kb,
    const bf16* __restrict__ Vtb, bf16* __restrict__ O) {
  __shared__ __align__(16) unsigned short P[4][64 * 72];  // per-wave P scratch, pad 64->72
  const int lane = threadIdx.x & 63;
  const int wv = threadIdx.x >> 6;
  const int quad = lane >> 4, l16 = lane & 15;
  const long w = blockIdx.x;
  unsigned short* Pw = &P[wv][0];
  const float SC = 0.17677669529663689f;  // 1/sqrt(32)
  const f32x4 fz = {0.f, 0.f, 0.f, 0.f};

#pragma unroll 1
  for (int hi = 0; hi < 2; ++hi) {
    const int h = wv * 2 + hi;
    const bf16* qp = Qb + ((w * 8 + h) * 64) * 32;
    const bf16* kp = Kb + ((w * 8 + h) * 64) * 32;
    const bf16* vt = Vtb + ((w * 8 + h) * 32) * 64;

    bf16x8 qf[4], kf[4];
#pragma unroll
    for (int mt = 0; mt < 4; ++mt)
      qf[mt] = *(const bf16x8*)(qp + (mt * 16 + l16) * 32 + quad * 8);
#pragma unroll
    for (int nt = 0; nt < 4; ++nt)
      kf[nt] = *(const bf16x8*)(kp + (nt * 16 + l16) * 32 + quad * 8);

    f32x4 s[4][4];
#pragma unroll
    for (int a = 0; a < 4; ++a) {
#pragma unroll
      for (int b = 0; b < 4; ++b) s[a][b] = fz;
    }
#pragma unroll
    for (int mt = 0; mt < 4; ++mt) {
#pragma unroll
      for (int nt = 0; nt < 4; ++nt) {
        s[mt][nt] = __builtin_amdgcn_mfma_f32_16x16x32_bf16(qf[mt], kf[nt],
                                                            s[mt][nt], 0, 0, 0);
      }
    }

    // row softmax: row = mt*16 + quad*4 + r, cols distributed over l16 x 4 tiles
#pragma unroll
    for (int mt = 0; mt < 4; ++mt) {
#pragma unroll
      for (int r = 0; r < 4; ++r) {
        float a0 = s[mt][0][r] * SC, a1 = s[mt][1][r] * SC;
        float a2 = s[mt][2][r] * SC, a3 = s[mt][3][r] * SC;
        float mx = fmaxf(fmaxf(a0, a1), fmaxf(a2, a3));
#pragma unroll
        for (int off = 8; off > 0; off >>= 1) mx = fmaxf(mx, __shfl_xor(mx, off));
        a0 = __expf(a0 - mx); a1 = __expf(a1 - mx);
        a2 = __expf(a2 - mx); a3 = __expf(a3 - mx);
        float sm = a0 + a1 + a2 + a3;
#pragma unroll
        for (int off = 8; off > 0; off >>= 1) sm += __shfl_xor(sm, off);
        const float iv = 1.0f / sm;
        const int rp = (mt * 16 + quad * 4 + r) * 72;
        Pw[rp + l16]      = bfbits(a0 * iv);
        Pw[rp + 16 + l16] = bfbits(a1 * iv);
        Pw[rp + 32 + l16] = bfbits(a2 * iv);
        Pw[rp + 48 + l16] = bfbits(a3 * iv);
      }
    }

    // PV: A = P (from LDS, A-layout), B = V^T fragments
    bf16x8 vf[2][2];
#pragma unroll
    for (int kt = 0; kt < 2; ++kt) {
#pragma unroll
      for (int dt = 0; dt < 2; ++dt)
        vf[kt][dt] = *(const bf16x8*)(vt + (dt * 16 + l16) * 64 + kt * 32 + quad * 8);
    }
    f32x4 oa[4][2];
#pragma unroll
    for (int a = 0; a < 4; ++a) { oa[a][0] = fz; oa[a][1] = fz; }
#pragma unroll
    for (int mt = 0; mt < 4; ++mt) {
      const unsigned short* pr = Pw + (mt * 16 + l16) * 72 + quad * 8;
      const bf16x8 p0 = *(const bf16x8*)(pr);
      const bf16x8 p1 = *(const bf16x8*)(pr + 32);
#pragma unroll
      for (int dt = 0; dt < 2; ++dt) {
        oa[mt][dt] = __builtin_amdgcn_mfma_f32_16x16x32_bf16(p0, vf[0][dt], oa[mt][dt], 0, 0, 0);
        oa[mt][dt] = __builtin_amdgcn_mfma_f32_16x16x32_bf16(p1, vf[1][dt], oa[mt][dt], 0, 0, 0);
      }
    }

    // store O in [window-token, C] layout (heads concatenated)
#pragma unroll
    for (int mt = 0; mt < 4; ++mt) {
#pragma unroll
      for (int dt = 0; dt < 2; ++dt) {
#pragma unroll
        for (int r = 0; r < 4; ++r) {
          O[(w * 64 + mt * 16 + quad * 4 + r) * 256 + h * 32 + dt * 16 + l16] =
              __float2bfloat16(oa[mt][dt][r]);
        }
      }
    }
  }
}

// ---------------- launch -----------------------------------------------------
extern "C" void kernel_launch(void* const* d_in, const int* in_sizes, int n_in,
                              void* d_out, int out_size, void* d_ws, size_t ws_size,
                              hipStream_t stream) {
  const float* x     = (const float*)d_in[0];
  const float* ln1g  = (const float*)d_in[1];
  const float* ln1b  = (const float*)d_in[2];
  const float* in_w  = (const float*)d_in[3];
  const float* in_b  = (const float*)d_in[4];
  const float* out_w = (const float*)d_in[5];
  const float* out_b = (const float*)d_in[6];
  const float* ln2g  = (const float*)d_in[7];
  const float* ln2b  = (const float*)d_in[8];
  const float* w1    = (const float*)d_in[9];
  const float* b1    = (const float*)d_in[10];
  const float* w2    = (const float*)d_in[11];
  const float* b2    = (const float*)d_in[12];
  float* out = (float*)d_out;

  char* ws = (char*)d_ws;
  const size_t MB = 1ull << 20;
  // ws layout (MiB): [0,2) weights bf16 | [2,66) xw -> o -> h | [66,130) Q
  // [130,194) K | [194,258) V^T | [66,322) h1 (overlays dead Q/K/V)
  bf16* Wc   = (bf16*)ws;
  bf16* Wqkv = Wc;
  bf16* Wo   = Wc + 196608;
  bf16* W1c  = Wc + 262144;
  bf16* W2c  = Wc + 524288;
  bf16* XW   = (bf16*)(ws + 2 * MB);
  bf16* Qb   = (bf16*)(ws + 66 * MB);
  bf16* Kb   = (bf16*)(ws + 130 * MB);
  bf16* Vtb  = (bf16*)(ws + 194 * MB);
  bf16* H1   = (bf16*)(ws + 66 * MB);
  bf16* Obuf = XW;  // xw dead after QKV gemm
  bf16* Hbuf = XW;  // o dead after out-proj

  cvt_w<<<3072, 256, 0, stream>>>(in_w, out_w, w1, w2, Wc);
  ln_kern<true><<<MTOK / 4, 256, 0, stream>>>(x, ln1g, ln1b, XW);
  gemm_bt<256, EPI_QKV><<<dim3(MTOK / 128, 6), 256, 0, stream>>>(
      XW, Wqkv, in_b, Qb, Kb, Vtb, nullptr, nullptr, nullptr, 0);
  attn_kern<<<2048, 256, 0, stream>>>(Qb, Kb, Vtb, Obuf);
  gemm_bt<256, EPI_OUTPROJ><<<dim3(MTOK / 128, 2), 256, 0, stream>>>(
      Obuf, Wo, out_b, nullptr, nullptr, nullptr, x, out, nullptr, 0);
  ln_kern<false><<<MTOK / 4, 256, 0, stream>>>(out, ln2g, ln2b, Hbuf);
  gemm_bt<256, EPI_GELU><<<dim3(MTOK / 128, 8), 256, 0, stream>>>(
      Hbuf, W1c, b1, nullptr, nullptr, nullptr, nullptr, nullptr, H1, 1024);
  gemm_bt<1024, EPI_RESID><<<dim3(MTOK / 128, 2), 256, 0, stream>>>(
      H1, W2c, b2, nullptr, nullptr, nullptr, nullptr, out, nullptr, 0);
}